// Round 7
// baseline (384.087 us; speedup 1.0000x reference)
//
#include <hip/hip_runtime.h>
#include <math.h>

#define NEG_SLOPE 0.2f
#define GAT_EPS 1e-16f
#define LOG2E 1.44269504088896340736f

#define CH   2048   // edges per chunk (831 blocks -> TLP for latency)
#define NBK  512    // fine buckets; bucket = d >> SHIFT (256 nodes/bucket at shift=8)
// Pack constraint: s < 2^17 (N <= 131072) and (d & mask) in bits 17..17+shift.

// ---- bf16 pair packing helpers (channel 2p in low half, 2p+1 in high) ----
__device__ __forceinline__ unsigned pack_bf16(float a, float b) {
    unsigned ua = __float_as_uint(a);
    unsigned ub = __float_as_uint(b);
    ua = (ua + 0x8000u) >> 16;
    ub = (ub + 0x8000u) & 0xffff0000u;
    return ua | ub;
}
__device__ __forceinline__ float bf_lo(unsigned pk) {
    return __uint_as_float(pk << 16);
}
__device__ __forceinline__ float bf_hi(unsigned pk) {
    return __uint_as_float(pk & 0xffff0000u);
}

// ===========================================================================
// CSR build via deterministic two-level counting sort — ZERO global atomics.
// (Round-5 lesson: direct atomic scatter = 109 MB dirty-line writes, 145 µs;
// the bucketed sort keeps csr_src writes window-local. Keep it.)
// ===========================================================================

// Pass B: PARALLEL per-bucket exclusive scan over chunks (block = bucket).
__global__ __launch_bounds__(256) void k_off_a(
    const int* __restrict__ cnt, int* __restrict__ off,
    int* __restrict__ tot, int NCHv)
{
    __shared__ int sm[256];
    int b = blockIdx.x;
    int t = threadIdx.x;
    int carry = 0;
    for (int c0 = 0; c0 < NCHv; c0 += 256) {
        int c = c0 + t;
        int v = (c < NCHv) ? cnt[c * NBK + b] : 0;
        sm[t] = v;
        __syncthreads();
        for (int o = 1; o < 256; o <<= 1) {
            int add = (t >= o) ? sm[t - o] : 0;
            __syncthreads();
            sm[t] += add;
            __syncthreads();
        }
        if (c < NCHv) off[c * NBK + b] = carry + sm[t] - v;  // exclusive
        carry += sm[255];
        __syncthreads();
    }
    if (t == 0) tot[b] = carry;
}

// Pass C: re-read chunk edges, rank via LDS cursors (bbase from tot-scan +
// off), write packed (s | (d&mask)<<17) into exclusive slab ranges.
__global__ __launch_bounds__(256) void k_place(
    const int* __restrict__ ei, int E, int N, int shift,
    const int* __restrict__ off, const int* __restrict__ tot,
    unsigned* __restrict__ bslab)
{
    __shared__ int cur[NBK];
    __shared__ int ps[256];
    int c = blockIdx.x;
    int t = threadIdx.x;
    int carry = 0;
    for (int b0 = 0; b0 < NBK; b0 += 256) {
        int v = tot[b0 + t];
        ps[t] = v;
        __syncthreads();
        for (int o = 1; o < 256; o <<= 1) {
            int u = (t >= o) ? ps[t - o] : 0;
            __syncthreads();
            ps[t] += u;
            __syncthreads();
        }
        cur[b0 + t] = carry + ps[t] - v + off[(size_t)c * NBK + b0 + t];
        carry += ps[255];
        __syncthreads();
    }
    __syncthreads();

    int Etot = E + N;
    int base = c * CH;
    int lim = min(base + CH, Etot);
    int mask = (1 << shift) - 1;
    for (int e = base + t; e < lim; e += 256) {
        int s, d;
        if (e < E) { s = ei[e]; d = ei[E + e]; }
        else       { s = e - E; d = s; }
        int b = d >> shift;
        int pos = atomicAdd(&cur[b], 1);  // LDS atomic
        bslab[pos] = (unsigned)s | ((unsigned)(d & mask) << 17);
    }
}

// Pass D: block per bucket: LDS fine histogram + scan -> row_ptr, then place
// srcs into the bucket's csr_src window (L2-local). LDS atomics only.
__global__ __launch_bounds__(256) void k_csr2(
    const int* __restrict__ tot, const unsigned* __restrict__ bslab,
    int shift, int* __restrict__ row_ptr, int* __restrict__ csr_src,
    int N, int Etot)
{
    __shared__ int sdeg[1024];
    __shared__ int scur[1024];
    __shared__ int ps[256];
    __shared__ int bb[NBK + 1];
    int b = blockIdx.x;
    int tid = threadIdx.x;

    // bbase from tot: 2-batch exclusive scan (coalesced, cheap)
    int carry = 0;
    for (int b0 = 0; b0 < NBK; b0 += 256) {
        int v = tot[b0 + tid];
        ps[tid] = v;
        __syncthreads();
        for (int o = 1; o < 256; o <<= 1) {
            int u = (tid >= o) ? ps[tid - o] : 0;
            __syncthreads();
            ps[tid] += u;
            __syncthreads();
        }
        bb[b0 + tid] = carry + ps[tid] - v;
        carry += ps[255];
        __syncthreads();
    }
    if (tid == 0) bb[NBK] = carry;
    __syncthreads();

    int beg = bb[b], end = bb[b + 1];
    int nodes = 1 << shift;            // 256 (shift=8); LDS sized for <=1024
    int node0 = b << shift;
    for (int i = tid; i < nodes; i += 256) sdeg[i] = 0;
    __syncthreads();
    for (int i = beg + tid; i < end; i += 256)
        atomicAdd(&sdeg[bslab[i] >> 17], 1);
    __syncthreads();
    int per = (nodes + 255) / 256;
    int mybase = tid * per;
    int sum = 0;
    for (int j = 0; j < per; j++) sum += sdeg[mybase + j];
    ps[tid] = sum;
    __syncthreads();
    int v0 = ps[tid];
    for (int o = 1; o < 256; o <<= 1) {
        int v = (tid >= o) ? ps[tid - o] : 0;
        __syncthreads();
        ps[tid] += v;
        __syncthreads();
    }
    int run = ps[tid] - v0;
    for (int j = 0; j < per; j++) {
        int i = mybase + j;
        int dgi = sdeg[i];
        scur[i] = beg + run;
        int node = node0 + i;
        if (node < N) row_ptr[node] = beg + run;
        run += dgi;
    }
    if (b == 0 && tid == 0) row_ptr[N] = Etot;
    __syncthreads();
    for (int i = beg + tid; i < end; i += 256) {
        unsigned w = bslab[i];
        int pos = atomicAdd(&scur[w >> 17], 1);  // LDS atomic
        csr_src[pos] = (int)(w & 0x1FFFFu);
    }
}

// ===========================================================================
// xl1 = x @ W1 [N,64] -> packed bf16; as1/ad1 logits (pre-scaled by log2e).
// REGISTER-BLOCKED: each thread computes 4 NODES x 16 CHANNELS (64 acc).
// First NCHv blocks also run the CSR pass-A chunk histogram.
// ===========================================================================
__device__ __forceinline__ void emit_node1(
    const float* acc, int n, int q, int c0,
    const float* asrc, const float* adst,
    unsigned* __restrict__ xl1b, float* __restrict__ as1,
    float* __restrict__ ad1)
{
    uint4 pk0, pk1;
    pk0.x = pack_bf16(acc[0], acc[1]);  pk0.y = pack_bf16(acc[2], acc[3]);
    pk0.z = pack_bf16(acc[4], acc[5]);  pk0.w = pack_bf16(acc[6], acc[7]);
    pk1.x = pack_bf16(acc[8], acc[9]);  pk1.y = pack_bf16(acc[10], acc[11]);
    pk1.z = pack_bf16(acc[12], acc[13]); pk1.w = pack_bf16(acc[14], acc[15]);
    uint4* xo = (uint4*)(xl1b + (size_t)n * 32 + q * 8);
    xo[0] = pk0;
    xo[1] = pk1;
#pragma unroll
    for (int hh = 0; hh < 2; hh++) {
        float s = 0.0f, t = 0.0f;
#pragma unroll
        for (int c = 0; c < 8; c++) {
            s = fmaf(acc[hh * 8 + c], asrc[c0 + hh * 8 + c], s);
            t = fmaf(acc[hh * 8 + c], adst[c0 + hh * 8 + c], t);
        }
        as1[(size_t)n * 8 + 2 * q + hh] = s * LOG2E;
        ad1[(size_t)n * 8 + 2 * q + hh] = t * LOG2E;
    }
}

__global__ __launch_bounds__(256) void k_gemm1(
    const float* __restrict__ x, const float* __restrict__ W1,
    const float* __restrict__ a_src1, const float* __restrict__ a_dst1,
    unsigned* __restrict__ xl1b, float* __restrict__ as1,
    float* __restrict__ ad1, int N, int F,
    const int* __restrict__ ei, int E, int shift, int NCHv,
    int* __restrict__ cnt)
{
    __shared__ float Ws[128 * 64];
    __shared__ float asrc[64];
    __shared__ float adst[64];
    __shared__ int hist[NBK];

    // ---- fused CSR pass A (chunk histogram) ----
    if (blockIdx.x < NCHv) {
        for (int i = threadIdx.x; i < NBK; i += 256) hist[i] = 0;
        __syncthreads();
        int Etot = E + N;
        int base = blockIdx.x * CH;
        int lim = min(base + CH, Etot);
        for (int e = base + threadIdx.x; e < lim; e += 256) {
            int d = (e < E) ? ei[E + e] : (e - E);
            atomicAdd(&hist[d >> shift], 1);
        }
        __syncthreads();
        for (int i = threadIdx.x; i < NBK; i += 256)
            cnt[(size_t)blockIdx.x * NBK + i] = hist[i];
    }
    if (blockIdx.x * 256 >= N) return;   // hist-only block

    // ---- GEMM part ----
    for (int i = threadIdx.x; i < F * 64; i += 256) Ws[i] = W1[i];
    if (threadIdx.x < 64) {
        asrc[threadIdx.x] = a_src1[threadIdx.x];
        adst[threadIdx.x] = a_dst1[threadIdx.x];
    }
    __syncthreads();

    int q = threadIdx.x & 3;              // channel quarter: 16q..16q+15
    int n0 = blockIdx.x * 256 + (threadIdx.x >> 2) * 4;  // 4 consecutive nodes
    if (n0 >= N) return;
    int c0 = q * 16;
    int n1 = min(n0 + 1, N - 1);
    int n2 = min(n0 + 2, N - 1);
    int n3 = min(n0 + 3, N - 1);

    float acc0[16], acc1[16], acc2[16], acc3[16];
#pragma unroll
    for (int c = 0; c < 16; c++) { acc0[c]=0.f; acc1[c]=0.f; acc2[c]=0.f; acc3[c]=0.f; }

    const float4* xr0 = (const float4*)(x + (size_t)n0 * F);
    const float4* xr1 = (const float4*)(x + (size_t)n1 * F);
    const float4* xr2 = (const float4*)(x + (size_t)n2 * F);
    const float4* xr3 = (const float4*)(x + (size_t)n3 * F);

#define GEMM1_ROW(comp, ridx)                                        \
    { const float* w = &Ws[(k4 * 4 + ridx) * 64 + c0];               \
      _Pragma("unroll")                                              \
      for (int c = 0; c < 16; c++) {                                 \
          float wc = w[c];                                           \
          acc0[c] = fmaf(xv0.comp, wc, acc0[c]);                     \
          acc1[c] = fmaf(xv1.comp, wc, acc1[c]);                     \
          acc2[c] = fmaf(xv2.comp, wc, acc2[c]);                     \
          acc3[c] = fmaf(xv3.comp, wc, acc3[c]); } }

    for (int k4 = 0; k4 < F / 4; k4++) {
        float4 xv0 = xr0[k4];
        float4 xv1 = xr1[k4];
        float4 xv2 = xr2[k4];
        float4 xv3 = xr3[k4];
        GEMM1_ROW(x, 0)
        GEMM1_ROW(y, 1)
        GEMM1_ROW(z, 2)
        GEMM1_ROW(w, 3)
    }
#undef GEMM1_ROW

    emit_node1(acc0, n0, q, c0, asrc, adst, xl1b, as1, ad1);
    if (n0 + 1 < N) emit_node1(acc1, n0 + 1, q, c0, asrc, adst, xl1b, as1, ad1);
    if (n0 + 2 < N) emit_node1(acc2, n0 + 2, q, c0, asrc, adst, xl1b, as1, ad1);
    if (n0 + 3 < N) emit_node1(acc3, n0 + 3, q, c0, asrc, adst, xl1b, as1, ad1);
}

// ===========================================================================
// FUSED layer-1 aggregation + layer-2 node transform. TWO DST NODES PER
// WAVE (32 lanes each: 4 edge groups x 8 channel lanes), 2-deep edge unroll
// (verified best; 4-deep was null -> gather is concurrency-limited).
// After the shfl_xor BUTTERFLY all 32 lanes hold the full ax/den sums, so
// the epilogue computes h=ELU(...) on every lane and does the 64x40 W2
// matvec cooperatively: lane (g,l) accumulates outputs 10g..10g+9 from its
// channels 8l..8l+7 (W2 in LDS), reduce over l (masks 1/2/4), logits reduce
// over g (masks 8/16). h1 NEVER MATERIALIZES (was 25.6 MB write + read).
// Writes compact xl2b rows (stride 24: 20 payload + as2 logit at uint 20)
// and ad2. xl2b/ad2 are SEPARATE storage (xl1b/ad1 still being gathered).
// ===========================================================================
__global__ __launch_bounds__(256) void k_agg1(
    const int* __restrict__ row_ptr, const int* __restrict__ csr_src,
    const float* __restrict__ as1, const float* __restrict__ ad1,
    const unsigned* __restrict__ xl1b, const float* __restrict__ b1,
    const float* __restrict__ W2, const float* __restrict__ a_src2,
    const float* __restrict__ a_dst2,
    unsigned* __restrict__ xl2b, float* __restrict__ ad2, int N)
{
    __shared__ float W2s[64 * 40];
    __shared__ float b1s[64];
    __shared__ float a2ss[40];
    __shared__ float a2ds[40];
    for (int i = threadIdx.x; i < 64 * 40; i += 256) W2s[i] = W2[i];
    if (threadIdx.x < 64) b1s[threadIdx.x] = b1[threadIdx.x];
    if (threadIdx.x < 40) {
        a2ss[threadIdx.x] = a_src2[threadIdx.x];
        a2ds[threadIdx.x] = a_dst2[threadIdx.x];
    }
    __syncthreads();

    int d = blockIdx.x * 8 + ((threadIdx.x >> 6) << 1) + ((threadIdx.x >> 5) & 1);
    if (d >= N) return;
    int lane = threadIdx.x & 31;   // lane within this dst's half-wave
    int g = lane >> 3;   // edge group 0..3
    int l = lane & 7;    // channel octet: channels 8l..8l+7

    int beg = row_ptr[d], end = row_ptr[d + 1];
    float adh = ad1[(size_t)d * 8 + l];

    float ax[8];
#pragma unroll
    for (int j = 0; j < 8; j++) ax[j] = 0.f;
    float den = 0.f;

    int i = beg + g;
    for (; i + 4 < end; i += 8) {
        int s0 = csr_src[i];
        int s1 = csr_src[i + 4];
        size_t q0 = (size_t)s0 * 8 + l;
        size_t q1 = (size_t)s1 * 8 + l;
        float al0 = as1[q0] + adh;
        float al1 = as1[q1] + adh;
        uint4 k0 = *(const uint4*)(xl1b + (q0 << 2));
        uint4 k1 = *(const uint4*)(xl1b + (q1 << 2));
        al0 = fmaxf(al0, NEG_SLOPE * al0);
        al1 = fmaxf(al1, NEG_SLOPE * al1);
        float e0 = __builtin_amdgcn_exp2f(al0);
        float e1 = __builtin_amdgcn_exp2f(al1);
        ax[0] = fmaf(e0, bf_lo(k0.x), ax[0]);
        ax[1] = fmaf(e0, bf_hi(k0.x), ax[1]);
        ax[2] = fmaf(e0, bf_lo(k0.y), ax[2]);
        ax[3] = fmaf(e0, bf_hi(k0.y), ax[3]);
        ax[4] = fmaf(e0, bf_lo(k0.z), ax[4]);
        ax[5] = fmaf(e0, bf_hi(k0.z), ax[5]);
        ax[6] = fmaf(e0, bf_lo(k0.w), ax[6]);
        ax[7] = fmaf(e0, bf_hi(k0.w), ax[7]);
        ax[0] = fmaf(e1, bf_lo(k1.x), ax[0]);
        ax[1] = fmaf(e1, bf_hi(k1.x), ax[1]);
        ax[2] = fmaf(e1, bf_lo(k1.y), ax[2]);
        ax[3] = fmaf(e1, bf_hi(k1.y), ax[3]);
        ax[4] = fmaf(e1, bf_lo(k1.z), ax[4]);
        ax[5] = fmaf(e1, bf_hi(k1.z), ax[5]);
        ax[6] = fmaf(e1, bf_lo(k1.w), ax[6]);
        ax[7] = fmaf(e1, bf_hi(k1.w), ax[7]);
        den += e0 + e1;
    }
    if (i < end) {
        int s0 = csr_src[i];
        size_t q0 = (size_t)s0 * 8 + l;
        float al0 = as1[q0] + adh;
        uint4 k0 = *(const uint4*)(xl1b + (q0 << 2));
        al0 = fmaxf(al0, NEG_SLOPE * al0);
        float e0 = __builtin_amdgcn_exp2f(al0);
        ax[0] = fmaf(e0, bf_lo(k0.x), ax[0]);
        ax[1] = fmaf(e0, bf_hi(k0.x), ax[1]);
        ax[2] = fmaf(e0, bf_lo(k0.y), ax[2]);
        ax[3] = fmaf(e0, bf_hi(k0.y), ax[3]);
        ax[4] = fmaf(e0, bf_lo(k0.z), ax[4]);
        ax[5] = fmaf(e0, bf_hi(k0.z), ax[5]);
        ax[6] = fmaf(e0, bf_lo(k0.w), ax[6]);
        ax[7] = fmaf(e0, bf_hi(k0.w), ax[7]);
        den += e0;
    }

    // Butterfly over the 4 edge groups: ALL lanes end with the full sums.
#pragma unroll
    for (int m = 8; m < 32; m <<= 1) {
#pragma unroll
        for (int j = 0; j < 8; j++) ax[j] += __shfl_xor(ax[j], m);
        den += __shfl_xor(den, m);
    }

    // ---- fused node2: h = ELU(ax*inv + b1); out = h @ W2 (64x40) ----
    float inv = __builtin_amdgcn_rcpf(den + GAT_EPS);
    float h[8];
#pragma unroll
    for (int j = 0; j < 8; j++) {
        float v = fmaf(ax[j], inv, b1s[l * 8 + j]);
        h[j] = v > 0.f ? v : __expf(v) - 1.f;
    }

    float pt[10];
#pragma unroll
    for (int jj = 0; jj < 10; jj++) pt[jj] = 0.f;
#pragma unroll
    for (int c = 0; c < 8; c++) {
        float hc = h[c];
        const float* wr = &W2s[(l * 8 + c) * 40 + g * 10];
#pragma unroll
        for (int jj = 0; jj < 10; jj++) pt[jj] = fmaf(hc, wr[jj], pt[jj]);
    }
    // reduce over channel octets l (masks 1,2,4 stay within the 8-lane octet)
#pragma unroll
    for (int m = 1; m < 8; m <<= 1) {
#pragma unroll
        for (int jj = 0; jj < 10; jj++) pt[jj] += __shfl_xor(pt[jj], m);
    }
    // logits over the full 40 outputs: per-g partial dot, reduce over g
    float s2 = 0.f, t2 = 0.f;
#pragma unroll
    for (int jj = 0; jj < 10; jj++) {
        s2 = fmaf(pt[jj], a2ss[g * 10 + jj], s2);
        t2 = fmaf(pt[jj], a2ds[g * 10 + jj], t2);
    }
    s2 += __shfl_xor(s2, 8);  s2 += __shfl_xor(s2, 16);
    t2 += __shfl_xor(t2, 8);  t2 += __shfl_xor(t2, 16);

    if (l == 0) {
        unsigned* xo = xl2b + (size_t)d * 24 + g * 5;
        xo[0] = pack_bf16(pt[0], pt[1]);
        xo[1] = pack_bf16(pt[2], pt[3]);
        xo[2] = pack_bf16(pt[4], pt[5]);
        xo[3] = pack_bf16(pt[6], pt[7]);
        xo[4] = pack_bf16(pt[8], pt[9]);
        if (g == 0) {
            xl2b[(size_t)d * 24 + 20] = __float_as_uint(s2 * LOG2E);
            ad2[d] = t2 * LOG2E;
        }
    }
}

// ===========================================================================
// Layer-2 aggregation (pull): TWO DST NODES PER WAVE, 2-deep edge unroll
// (verified best). Rows stride 24: lane l<5 loads uint4 at +4l; the as2
// logit is row[20] (same line as lane 4's quad). Lanes l>=5 predicated off.
// ===========================================================================
__global__ __launch_bounds__(256) void k_agg2(
    const int* __restrict__ row_ptr, const int* __restrict__ csr_src,
    const float* __restrict__ ad2,
    const unsigned* __restrict__ xl2b, const float* __restrict__ b2,
    float* __restrict__ out, int N)
{
    int d = blockIdx.x * 8 + ((threadIdx.x >> 6) << 1) + ((threadIdx.x >> 5) & 1);
    if (d >= N) return;
    int lane = threadIdx.x & 31;
    int g = lane >> 3;   // edge group 0..3
    int l = lane & 7;
    if (l >= 5) return;  // only 5 octets of 40 channels; reduction is l-local

    int beg = row_ptr[d], end = row_ptr[d + 1];
    float add = ad2[d];

    float ax[8];
#pragma unroll
    for (int j = 0; j < 8; j++) ax[j] = 0.f;
    float den = 0.f;

    int i = beg + g;
    for (; i + 4 < end; i += 8) {
        int s0 = csr_src[i];
        int s1 = csr_src[i + 4];
        const unsigned* r0 = xl2b + (size_t)s0 * 24;
        const unsigned* r1 = xl2b + (size_t)s1 * 24;
        float al0 = __uint_as_float(r0[20]) + add;
        float al1 = __uint_as_float(r1[20]) + add;
        uint4 k0 = *(const uint4*)(r0 + l * 4);
        uint4 k1 = *(const uint4*)(r1 + l * 4);
        al0 = fmaxf(al0, NEG_SLOPE * al0);
        al1 = fmaxf(al1, NEG_SLOPE * al1);
        float e0 = __builtin_amdgcn_exp2f(al0);
        float e1 = __builtin_amdgcn_exp2f(al1);
        ax[0] = fmaf(e0, bf_lo(k0.x), ax[0]);
        ax[1] = fmaf(e0, bf_hi(k0.x), ax[1]);
        ax[2] = fmaf(e0, bf_lo(k0.y), ax[2]);
        ax[3] = fmaf(e0, bf_hi(k0.y), ax[3]);
        ax[4] = fmaf(e0, bf_lo(k0.z), ax[4]);
        ax[5] = fmaf(e0, bf_hi(k0.z), ax[5]);
        ax[6] = fmaf(e0, bf_lo(k0.w), ax[6]);
        ax[7] = fmaf(e0, bf_hi(k0.w), ax[7]);
        ax[0] = fmaf(e1, bf_lo(k1.x), ax[0]);
        ax[1] = fmaf(e1, bf_hi(k1.x), ax[1]);
        ax[2] = fmaf(e1, bf_lo(k1.y), ax[2]);
        ax[3] = fmaf(e1, bf_hi(k1.y), ax[3]);
        ax[4] = fmaf(e1, bf_lo(k1.z), ax[4]);
        ax[5] = fmaf(e1, bf_hi(k1.z), ax[5]);
        ax[6] = fmaf(e1, bf_lo(k1.w), ax[6]);
        ax[7] = fmaf(e1, bf_hi(k1.w), ax[7]);
        den += e0 + e1;
    }
    if (i < end) {
        int s0 = csr_src[i];
        const unsigned* r0 = xl2b + (size_t)s0 * 24;
        float al0 = __uint_as_float(r0[20]) + add;
        uint4 k0 = *(const uint4*)(r0 + l * 4);
        al0 = fmaxf(al0, NEG_SLOPE * al0);
        float e0 = __builtin_amdgcn_exp2f(al0);
        ax[0] = fmaf(e0, bf_lo(k0.x), ax[0]);
        ax[1] = fmaf(e0, bf_hi(k0.x), ax[1]);
        ax[2] = fmaf(e0, bf_lo(k0.y), ax[2]);
        ax[3] = fmaf(e0, bf_hi(k0.y), ax[3]);
        ax[4] = fmaf(e0, bf_lo(k0.z), ax[4]);
        ax[5] = fmaf(e0, bf_hi(k0.z), ax[5]);
        ax[6] = fmaf(e0, bf_lo(k0.w), ax[6]);
        ax[7] = fmaf(e0, bf_hi(k0.w), ax[7]);
        den += e0;
    }

#pragma unroll
    for (int m = 8; m < 32; m <<= 1) {
#pragma unroll
        for (int j = 0; j < 8; j++) ax[j] += __shfl_xor(ax[j], m);
        den += __shfl_xor(den, m);
    }

    if (g == 0) {
        float inv = __builtin_amdgcn_rcpf(den + GAT_EPS);
        float* op = out + (size_t)d * 40 + l * 8;
        const float* bb = b2 + l * 8;
#pragma unroll
        for (int j = 0; j < 8; j++) op[j] = fmaf(ax[j], inv, bb[j]);
    }
}

extern "C" void kernel_launch(void* const* d_in, const int* in_sizes, int n_in,
                              void* d_out, int out_size, void* d_ws, size_t ws_size,
                              hipStream_t stream) {
    const float* x      = (const float*)d_in[0];
    const int*   ei     = (const int*)d_in[1];     // int32 on device
    const float* W1     = (const float*)d_in[2];
    const float* a_src1 = (const float*)d_in[3];
    const float* a_dst1 = (const float*)d_in[4];
    const float* b1     = (const float*)d_in[5];
    const float* W2     = (const float*)d_in[6];
    const float* a_src2 = (const float*)d_in[7];
    const float* a_dst2 = (const float*)d_in[8];
    const float* b2     = (const float*)d_in[9];

    int F = in_sizes[2] / 64;      // 128
    int N = in_sizes[0] / F;       // 100000
    int E = in_sizes[1] / 2;       // 1600000
    int Etot = E + N;
    int NCHv = (Etot + CH - 1) / CH;  // 831 chunks
    int shift = 8;                    // 256 nodes/bucket; 391 buckets used
    while (((N - 1) >> shift) >= NBK) shift++;  // safety (LDS supports shift<=10)

    // Workspace (4-byte words). h1 is GONE (fused); xl2b/ad2 are now
    // separate storage (xl1b/ad1 are still live while agg1 writes them).
    // Total ~47 MB (< the ~59 MB the previous layout used successfully).
    unsigned* xl1b    = (unsigned*)d_ws;                   // N*32
    float*    as1     = (float*)(xl1b + (size_t)N * 32);   // N*8
    float*    ad1     = as1 + (size_t)N * 8;               // N*8
    int*      row_ptr = (int*)(ad1 + (size_t)N * 8);       // N+1
    int*      csr_src = row_ptr + (N + 1);                 // Etot
    unsigned* bslab   = (unsigned*)(csr_src + Etot);       // Etot
    int*      cnt     = (int*)(bslab + Etot);              // NCHv*NBK
    int*      off     = cnt + (size_t)NCHv * NBK;          // NCHv*NBK
    int*      tot     = off + (size_t)NCHv * NBK;          // NBK
    unsigned* xl2b    = (unsigned*)(tot + NBK);            // N*24 rows (96 B)
    float*    ad2     = (float*)(xl2b + (size_t)N * 24);   // N

    // ---- Layer-1 GEMM (256 nodes/block) + fused CSR pass A ----
    int gridG1 = (N + 255) / 256;
    if (gridG1 < NCHv) gridG1 = NCHv;
    k_gemm1<<<gridG1, 256, 0, stream>>>(x, W1, a_src1, a_dst1,
                                        xl1b, as1, ad1, N, F,
                                        ei, E, shift, NCHv, cnt);

    // ---- CSR build: deterministic counting sort, zero global atomics ----
    k_off_a<<<NBK, 256, 0, stream>>>(cnt, off, tot, NCHv);
    k_place<<<NCHv, 256, 0, stream>>>(ei, E, N, shift, off, tot, bslab);
    k_csr2 <<<NBK, 256, 0, stream>>>(tot, bslab, shift,
                                     row_ptr, csr_src, N, Etot);

    // ---- Layer-1 aggregation FUSED with layer-2 node transform ----
    k_agg1 <<<(N + 7) / 8, 256, 0, stream>>>(row_ptr, csr_src, as1, ad1,
                                             xl1b, b1, W2, a_src2, a_dst2,
                                             xl2b, ad2, N);

    // ---- Layer-2 aggregation ----
    k_agg2 <<<(N + 7) / 8, 256, 0, stream>>>(row_ptr, csr_src, ad2,
                                             xl2b, b2, (float*)d_out, N);
}

// Round 8
// 310.328 us; speedup vs baseline: 1.2377x; 1.2377x over previous
//
#include <hip/hip_runtime.h>
#include <math.h>

#define NEG_SLOPE 0.2f
#define GAT_EPS 1e-16f
#define LOG2E 1.44269504088896340736f

#define CH   2048   // edges per chunk (831 blocks -> TLP for latency)
#define NBK  512    // fine buckets; bucket = d >> SHIFT (256 nodes/bucket at shift=8)
#define W2P  41     // padded LDS stride for W2 tile: (8l)*41*8? -> bank=(8l+9c+10g+jj)%32,
                    // uniform 2-way (free, m136). Stride 40 was 8-way (5.6e7 conflicts, R7).
// Pack constraint: s < 2^17 (N <= 131072) and (d & mask) in bits 17..17+shift.

// ---- bf16 pair packing helpers (channel 2p in low half, 2p+1 in high) ----
__device__ __forceinline__ unsigned pack_bf16(float a, float b) {
    unsigned ua = __float_as_uint(a);
    unsigned ub = __float_as_uint(b);
    ua = (ua + 0x8000u) >> 16;
    ub = (ub + 0x8000u) & 0xffff0000u;
    return ua | ub;
}
__device__ __forceinline__ float bf_lo(unsigned pk) {
    return __uint_as_float(pk << 16);
}
__device__ __forceinline__ float bf_hi(unsigned pk) {
    return __uint_as_float(pk & 0xffff0000u);
}

// ===========================================================================
// CSR build via deterministic two-level counting sort — ZERO global atomics.
// (Round-5 lesson: direct atomic scatter = 109 MB dirty-line writes, 145 µs;
// the bucketed sort keeps csr_src writes window-local. Keep it.)
// ===========================================================================

// Pass B: PARALLEL per-bucket exclusive scan over chunks (block = bucket).
__global__ __launch_bounds__(256) void k_off_a(
    const int* __restrict__ cnt, int* __restrict__ off,
    int* __restrict__ tot, int NCHv)
{
    __shared__ int sm[256];
    int b = blockIdx.x;
    int t = threadIdx.x;
    int carry = 0;
    for (int c0 = 0; c0 < NCHv; c0 += 256) {
        int c = c0 + t;
        int v = (c < NCHv) ? cnt[c * NBK + b] : 0;
        sm[t] = v;
        __syncthreads();
        for (int o = 1; o < 256; o <<= 1) {
            int add = (t >= o) ? sm[t - o] : 0;
            __syncthreads();
            sm[t] += add;
            __syncthreads();
        }
        if (c < NCHv) off[c * NBK + b] = carry + sm[t] - v;  // exclusive
        carry += sm[255];
        __syncthreads();
    }
    if (t == 0) tot[b] = carry;
}

// Pass C: re-read chunk edges, rank via LDS cursors (bbase from tot-scan +
// off), write packed (s | (d&mask)<<17) into exclusive slab ranges.
__global__ __launch_bounds__(256) void k_place(
    const int* __restrict__ ei, int E, int N, int shift,
    const int* __restrict__ off, const int* __restrict__ tot,
    unsigned* __restrict__ bslab)
{
    __shared__ int cur[NBK];
    __shared__ int ps[256];
    int c = blockIdx.x;
    int t = threadIdx.x;
    int carry = 0;
    for (int b0 = 0; b0 < NBK; b0 += 256) {
        int v = tot[b0 + t];
        ps[t] = v;
        __syncthreads();
        for (int o = 1; o < 256; o <<= 1) {
            int u = (t >= o) ? ps[t - o] : 0;
            __syncthreads();
            ps[t] += u;
            __syncthreads();
        }
        cur[b0 + t] = carry + ps[t] - v + off[(size_t)c * NBK + b0 + t];
        carry += ps[255];
        __syncthreads();
    }
    __syncthreads();

    int Etot = E + N;
    int base = c * CH;
    int lim = min(base + CH, Etot);
    int mask = (1 << shift) - 1;
    for (int e = base + t; e < lim; e += 256) {
        int s, d;
        if (e < E) { s = ei[e]; d = ei[E + e]; }
        else       { s = e - E; d = s; }
        int b = d >> shift;
        int pos = atomicAdd(&cur[b], 1);  // LDS atomic
        bslab[pos] = (unsigned)s | ((unsigned)(d & mask) << 17);
    }
}

// Pass D: block per bucket: LDS fine histogram + scan -> row_ptr, then place
// srcs into the bucket's csr_src window (L2-local). LDS atomics only.
__global__ __launch_bounds__(256) void k_csr2(
    const int* __restrict__ tot, const unsigned* __restrict__ bslab,
    int shift, int* __restrict__ row_ptr, int* __restrict__ csr_src,
    int N, int Etot)
{
    __shared__ int sdeg[1024];
    __shared__ int scur[1024];
    __shared__ int ps[256];
    __shared__ int bb[NBK + 1];
    int b = blockIdx.x;
    int tid = threadIdx.x;

    // bbase from tot: 2-batch exclusive scan (coalesced, cheap)
    int carry = 0;
    for (int b0 = 0; b0 < NBK; b0 += 256) {
        int v = tot[b0 + tid];
        ps[tid] = v;
        __syncthreads();
        for (int o = 1; o < 256; o <<= 1) {
            int u = (tid >= o) ? ps[tid - o] : 0;
            __syncthreads();
            ps[tid] += u;
            __syncthreads();
        }
        bb[b0 + tid] = carry + ps[tid] - v;
        carry += ps[255];
        __syncthreads();
    }
    if (tid == 0) bb[NBK] = carry;
    __syncthreads();

    int beg = bb[b], end = bb[b + 1];
    int nodes = 1 << shift;            // 256 (shift=8); LDS sized for <=1024
    int node0 = b << shift;
    for (int i = tid; i < nodes; i += 256) sdeg[i] = 0;
    __syncthreads();
    for (int i = beg + tid; i < end; i += 256)
        atomicAdd(&sdeg[bslab[i] >> 17], 1);
    __syncthreads();
    int per = (nodes + 255) / 256;
    int mybase = tid * per;
    int sum = 0;
    for (int j = 0; j < per; j++) sum += sdeg[mybase + j];
    ps[tid] = sum;
    __syncthreads();
    int v0 = ps[tid];
    for (int o = 1; o < 256; o <<= 1) {
        int v = (tid >= o) ? ps[tid - o] : 0;
        __syncthreads();
        ps[tid] += v;
        __syncthreads();
    }
    int run = ps[tid] - v0;
    for (int j = 0; j < per; j++) {
        int i = mybase + j;
        int dgi = sdeg[i];
        scur[i] = beg + run;
        int node = node0 + i;
        if (node < N) row_ptr[node] = beg + run;
        run += dgi;
    }
    if (b == 0 && tid == 0) row_ptr[N] = Etot;
    __syncthreads();
    for (int i = beg + tid; i < end; i += 256) {
        unsigned w = bslab[i];
        int pos = atomicAdd(&scur[w >> 17], 1);  // LDS atomic
        csr_src[pos] = (int)(w & 0x1FFFFu);
    }
}

// ===========================================================================
// xl1 = x @ W1 [N,64] -> packed bf16; as1/ad1 logits (pre-scaled by log2e).
// REGISTER-BLOCKED: each thread computes 4 NODES x 16 CHANNELS (64 acc).
// First NCHv blocks also run the CSR pass-A chunk histogram.
// ===========================================================================
__device__ __forceinline__ void emit_node1(
    const float* acc, int n, int q, int c0,
    const float* asrc, const float* adst,
    unsigned* __restrict__ xl1b, float* __restrict__ as1,
    float* __restrict__ ad1)
{
    uint4 pk0, pk1;
    pk0.x = pack_bf16(acc[0], acc[1]);  pk0.y = pack_bf16(acc[2], acc[3]);
    pk0.z = pack_bf16(acc[4], acc[5]);  pk0.w = pack_bf16(acc[6], acc[7]);
    pk1.x = pack_bf16(acc[8], acc[9]);  pk1.y = pack_bf16(acc[10], acc[11]);
    pk1.z = pack_bf16(acc[12], acc[13]); pk1.w = pack_bf16(acc[14], acc[15]);
    uint4* xo = (uint4*)(xl1b + (size_t)n * 32 + q * 8);
    xo[0] = pk0;
    xo[1] = pk1;
#pragma unroll
    for (int hh = 0; hh < 2; hh++) {
        float s = 0.0f, t = 0.0f;
#pragma unroll
        for (int c = 0; c < 8; c++) {
            s = fmaf(acc[hh * 8 + c], asrc[c0 + hh * 8 + c], s);
            t = fmaf(acc[hh * 8 + c], adst[c0 + hh * 8 + c], t);
        }
        as1[(size_t)n * 8 + 2 * q + hh] = s * LOG2E;
        ad1[(size_t)n * 8 + 2 * q + hh] = t * LOG2E;
    }
}

__global__ __launch_bounds__(256) void k_gemm1(
    const float* __restrict__ x, const float* __restrict__ W1,
    const float* __restrict__ a_src1, const float* __restrict__ a_dst1,
    unsigned* __restrict__ xl1b, float* __restrict__ as1,
    float* __restrict__ ad1, int N, int F,
    const int* __restrict__ ei, int E, int shift, int NCHv,
    int* __restrict__ cnt)
{
    __shared__ float Ws[128 * 64];
    __shared__ float asrc[64];
    __shared__ float adst[64];
    __shared__ int hist[NBK];

    // ---- fused CSR pass A (chunk histogram) ----
    if (blockIdx.x < NCHv) {
        for (int i = threadIdx.x; i < NBK; i += 256) hist[i] = 0;
        __syncthreads();
        int Etot = E + N;
        int base = blockIdx.x * CH;
        int lim = min(base + CH, Etot);
        for (int e = base + threadIdx.x; e < lim; e += 256) {
            int d = (e < E) ? ei[E + e] : (e - E);
            atomicAdd(&hist[d >> shift], 1);
        }
        __syncthreads();
        for (int i = threadIdx.x; i < NBK; i += 256)
            cnt[(size_t)blockIdx.x * NBK + i] = hist[i];
    }
    if (blockIdx.x * 256 >= N) return;   // hist-only block

    // ---- GEMM part ----
    for (int i = threadIdx.x; i < F * 64; i += 256) Ws[i] = W1[i];
    if (threadIdx.x < 64) {
        asrc[threadIdx.x] = a_src1[threadIdx.x];
        adst[threadIdx.x] = a_dst1[threadIdx.x];
    }
    __syncthreads();

    int q = threadIdx.x & 3;              // channel quarter: 16q..16q+15
    int n0 = blockIdx.x * 256 + (threadIdx.x >> 2) * 4;  // 4 consecutive nodes
    if (n0 >= N) return;
    int c0 = q * 16;
    int n1 = min(n0 + 1, N - 1);
    int n2 = min(n0 + 2, N - 1);
    int n3 = min(n0 + 3, N - 1);

    float acc0[16], acc1[16], acc2[16], acc3[16];
#pragma unroll
    for (int c = 0; c < 16; c++) { acc0[c]=0.f; acc1[c]=0.f; acc2[c]=0.f; acc3[c]=0.f; }

    const float4* xr0 = (const float4*)(x + (size_t)n0 * F);
    const float4* xr1 = (const float4*)(x + (size_t)n1 * F);
    const float4* xr2 = (const float4*)(x + (size_t)n2 * F);
    const float4* xr3 = (const float4*)(x + (size_t)n3 * F);

#define GEMM1_ROW(comp, ridx)                                        \
    { const float* w = &Ws[(k4 * 4 + ridx) * 64 + c0];               \
      _Pragma("unroll")                                              \
      for (int c = 0; c < 16; c++) {                                 \
          float wc = w[c];                                           \
          acc0[c] = fmaf(xv0.comp, wc, acc0[c]);                     \
          acc1[c] = fmaf(xv1.comp, wc, acc1[c]);                     \
          acc2[c] = fmaf(xv2.comp, wc, acc2[c]);                     \
          acc3[c] = fmaf(xv3.comp, wc, acc3[c]); } }

    for (int k4 = 0; k4 < F / 4; k4++) {
        float4 xv0 = xr0[k4];
        float4 xv1 = xr1[k4];
        float4 xv2 = xr2[k4];
        float4 xv3 = xr3[k4];
        GEMM1_ROW(x, 0)
        GEMM1_ROW(y, 1)
        GEMM1_ROW(z, 2)
        GEMM1_ROW(w, 3)
    }
#undef GEMM1_ROW

    emit_node1(acc0, n0, q, c0, asrc, adst, xl1b, as1, ad1);
    if (n0 + 1 < N) emit_node1(acc1, n0 + 1, q, c0, asrc, adst, xl1b, as1, ad1);
    if (n0 + 2 < N) emit_node1(acc2, n0 + 2, q, c0, asrc, adst, xl1b, as1, ad1);
    if (n0 + 3 < N) emit_node1(acc3, n0 + 3, q, c0, asrc, adst, xl1b, as1, ad1);
}

// ===========================================================================
// FUSED layer-1 aggregation + layer-2 node transform. TWO DST NODES PER
// WAVE (32 lanes each: 4 edge groups x 8 channel lanes), 2-deep edge unroll.
// After the shfl_xor butterfly ALL lanes hold the full ax/den sums; the
// epilogue computes h=ELU(...) on every lane and does the 64x40 W2 matvec
// cooperatively: lane (g,l) accumulates outputs 10g..10g+9 from channels
// 8l..8l+7 (W2 in LDS, PADDED stride 41 -> uniform 2-way bank access, free;
// stride 40 was an 8-way same-bank conflict = R7's 5.6e7-conflict 3.2x
// regression), reduce over l (masks 1/2/4), logits over g (masks 8/16).
// h1 never materializes. Writes compact xl2b rows (stride 24) + ad2.
// ===========================================================================
__global__ __launch_bounds__(256) void k_agg1(
    const int* __restrict__ row_ptr, const int* __restrict__ csr_src,
    const float* __restrict__ as1, const float* __restrict__ ad1,
    const unsigned* __restrict__ xl1b, const float* __restrict__ b1,
    const float* __restrict__ W2, const float* __restrict__ a_src2,
    const float* __restrict__ a_dst2,
    unsigned* __restrict__ xl2b, float* __restrict__ ad2, int N)
{
    __shared__ float W2s[64 * W2P];
    __shared__ float b1s[64];
    __shared__ float a2ss[40];
    __shared__ float a2ds[40];
    for (int i = threadIdx.x; i < 64 * 40; i += 256)
        W2s[(i / 40) * W2P + (i % 40)] = W2[i];
    if (threadIdx.x < 64) b1s[threadIdx.x] = b1[threadIdx.x];
    if (threadIdx.x < 40) {
        a2ss[threadIdx.x] = a_src2[threadIdx.x];
        a2ds[threadIdx.x] = a_dst2[threadIdx.x];
    }
    __syncthreads();

    int d = blockIdx.x * 8 + ((threadIdx.x >> 6) << 1) + ((threadIdx.x >> 5) & 1);
    if (d >= N) return;
    int lane = threadIdx.x & 31;   // lane within this dst's half-wave
    int g = lane >> 3;   // edge group 0..3
    int l = lane & 7;    // channel octet: channels 8l..8l+7

    int beg = row_ptr[d], end = row_ptr[d + 1];
    float adh = ad1[(size_t)d * 8 + l];

    float ax[8];
#pragma unroll
    for (int j = 0; j < 8; j++) ax[j] = 0.f;
    float den = 0.f;

    int i = beg + g;
    for (; i + 4 < end; i += 8) {
        int s0 = csr_src[i];
        int s1 = csr_src[i + 4];
        size_t q0 = (size_t)s0 * 8 + l;
        size_t q1 = (size_t)s1 * 8 + l;
        float al0 = as1[q0] + adh;
        float al1 = as1[q1] + adh;
        uint4 k0 = *(const uint4*)(xl1b + (q0 << 2));
        uint4 k1 = *(const uint4*)(xl1b + (q1 << 2));
        al0 = fmaxf(al0, NEG_SLOPE * al0);
        al1 = fmaxf(al1, NEG_SLOPE * al1);
        float e0 = __builtin_amdgcn_exp2f(al0);
        float e1 = __builtin_amdgcn_exp2f(al1);
        ax[0] = fmaf(e0, bf_lo(k0.x), ax[0]);
        ax[1] = fmaf(e0, bf_hi(k0.x), ax[1]);
        ax[2] = fmaf(e0, bf_lo(k0.y), ax[2]);
        ax[3] = fmaf(e0, bf_hi(k0.y), ax[3]);
        ax[4] = fmaf(e0, bf_lo(k0.z), ax[4]);
        ax[5] = fmaf(e0, bf_hi(k0.z), ax[5]);
        ax[6] = fmaf(e0, bf_lo(k0.w), ax[6]);
        ax[7] = fmaf(e0, bf_hi(k0.w), ax[7]);
        ax[0] = fmaf(e1, bf_lo(k1.x), ax[0]);
        ax[1] = fmaf(e1, bf_hi(k1.x), ax[1]);
        ax[2] = fmaf(e1, bf_lo(k1.y), ax[2]);
        ax[3] = fmaf(e1, bf_hi(k1.y), ax[3]);
        ax[4] = fmaf(e1, bf_lo(k1.z), ax[4]);
        ax[5] = fmaf(e1, bf_hi(k1.z), ax[5]);
        ax[6] = fmaf(e1, bf_lo(k1.w), ax[6]);
        ax[7] = fmaf(e1, bf_hi(k1.w), ax[7]);
        den += e0 + e1;
    }
    if (i < end) {
        int s0 = csr_src[i];
        size_t q0 = (size_t)s0 * 8 + l;
        float al0 = as1[q0] + adh;
        uint4 k0 = *(const uint4*)(xl1b + (q0 << 2));
        al0 = fmaxf(al0, NEG_SLOPE * al0);
        float e0 = __builtin_amdgcn_exp2f(al0);
        ax[0] = fmaf(e0, bf_lo(k0.x), ax[0]);
        ax[1] = fmaf(e0, bf_hi(k0.x), ax[1]);
        ax[2] = fmaf(e0, bf_lo(k0.y), ax[2]);
        ax[3] = fmaf(e0, bf_hi(k0.y), ax[3]);
        ax[4] = fmaf(e0, bf_lo(k0.z), ax[4]);
        ax[5] = fmaf(e0, bf_hi(k0.z), ax[5]);
        ax[6] = fmaf(e0, bf_lo(k0.w), ax[6]);
        ax[7] = fmaf(e0, bf_hi(k0.w), ax[7]);
        den += e0;
    }

    // Butterfly over the 4 edge groups: ALL lanes end with the full sums.
#pragma unroll
    for (int m = 8; m < 32; m <<= 1) {
#pragma unroll
        for (int j = 0; j < 8; j++) ax[j] += __shfl_xor(ax[j], m);
        den += __shfl_xor(den, m);
    }

    // ---- fused node2: h = ELU(ax*inv + b1); out = h @ W2 (64x40) ----
    float inv = __builtin_amdgcn_rcpf(den + GAT_EPS);
    float h[8];
#pragma unroll
    for (int j = 0; j < 8; j++) {
        float v = fmaf(ax[j], inv, b1s[l * 8 + j]);
        h[j] = v > 0.f ? v : __expf(v) - 1.f;
    }

    float pt[10];
#pragma unroll
    for (int jj = 0; jj < 10; jj++) pt[jj] = 0.f;
#pragma unroll
    for (int c = 0; c < 8; c++) {
        float hc = h[c];
        const float* wr = &W2s[(l * 8 + c) * W2P + g * 10];
#pragma unroll
        for (int jj = 0; jj < 10; jj++) pt[jj] = fmaf(hc, wr[jj], pt[jj]);
    }
    // reduce over channel octets l (masks 1,2,4 stay within the 8-lane octet)
#pragma unroll
    for (int m = 1; m < 8; m <<= 1) {
#pragma unroll
        for (int jj = 0; jj < 10; jj++) pt[jj] += __shfl_xor(pt[jj], m);
    }
    // logits over the full 40 outputs: per-g partial dot, reduce over g
    float s2 = 0.f, t2 = 0.f;
#pragma unroll
    for (int jj = 0; jj < 10; jj++) {
        s2 = fmaf(pt[jj], a2ss[g * 10 + jj], s2);
        t2 = fmaf(pt[jj], a2ds[g * 10 + jj], t2);
    }
    s2 += __shfl_xor(s2, 8);  s2 += __shfl_xor(s2, 16);
    t2 += __shfl_xor(t2, 8);  t2 += __shfl_xor(t2, 16);

    if (l == 0) {
        unsigned* xo = xl2b + (size_t)d * 24 + g * 5;
        xo[0] = pack_bf16(pt[0], pt[1]);
        xo[1] = pack_bf16(pt[2], pt[3]);
        xo[2] = pack_bf16(pt[4], pt[5]);
        xo[3] = pack_bf16(pt[6], pt[7]);
        xo[4] = pack_bf16(pt[8], pt[9]);
        if (g == 0) {
            xl2b[(size_t)d * 24 + 20] = __float_as_uint(s2 * LOG2E);
            ad2[d] = t2 * LOG2E;
        }
    }
}

// ===========================================================================
// Layer-2 aggregation (pull): TWO DST NODES PER WAVE, 2-deep edge unroll
// (verified best). Rows stride 24: lane l<5 loads uint4 at +4l; the as2
// logit is row[20] (same line as lane 4's quad). Lanes l>=5 predicated off.
// ===========================================================================
__global__ __launch_bounds__(256) void k_agg2(
    const int* __restrict__ row_ptr, const int* __restrict__ csr_src,
    const float* __restrict__ ad2,
    const unsigned* __restrict__ xl2b, const float* __restrict__ b2,
    float* __restrict__ out, int N)
{
    int d = blockIdx.x * 8 + ((threadIdx.x >> 6) << 1) + ((threadIdx.x >> 5) & 1);
    if (d >= N) return;
    int lane = threadIdx.x & 31;
    int g = lane >> 3;   // edge group 0..3
    int l = lane & 7;
    if (l >= 5) return;  // only 5 octets of 40 channels; reduction is l-local

    int beg = row_ptr[d], end = row_ptr[d + 1];
    float add = ad2[d];

    float ax[8];
#pragma unroll
    for (int j = 0; j < 8; j++) ax[j] = 0.f;
    float den = 0.f;

    int i = beg + g;
    for (; i + 4 < end; i += 8) {
        int s0 = csr_src[i];
        int s1 = csr_src[i + 4];
        const unsigned* r0 = xl2b + (size_t)s0 * 24;
        const unsigned* r1 = xl2b + (size_t)s1 * 24;
        float al0 = __uint_as_float(r0[20]) + add;
        float al1 = __uint_as_float(r1[20]) + add;
        uint4 k0 = *(const uint4*)(r0 + l * 4);
        uint4 k1 = *(const uint4*)(r1 + l * 4);
        al0 = fmaxf(al0, NEG_SLOPE * al0);
        al1 = fmaxf(al1, NEG_SLOPE * al1);
        float e0 = __builtin_amdgcn_exp2f(al0);
        float e1 = __builtin_amdgcn_exp2f(al1);
        ax[0] = fmaf(e0, bf_lo(k0.x), ax[0]);
        ax[1] = fmaf(e0, bf_hi(k0.x), ax[1]);
        ax[2] = fmaf(e0, bf_lo(k0.y), ax[2]);
        ax[3] = fmaf(e0, bf_hi(k0.y), ax[3]);
        ax[4] = fmaf(e0, bf_lo(k0.z), ax[4]);
        ax[5] = fmaf(e0, bf_hi(k0.z), ax[5]);
        ax[6] = fmaf(e0, bf_lo(k0.w), ax[6]);
        ax[7] = fmaf(e0, bf_hi(k0.w), ax[7]);
        ax[0] = fmaf(e1, bf_lo(k1.x), ax[0]);
        ax[1] = fmaf(e1, bf_hi(k1.x), ax[1]);
        ax[2] = fmaf(e1, bf_lo(k1.y), ax[2]);
        ax[3] = fmaf(e1, bf_hi(k1.y), ax[3]);
        ax[4] = fmaf(e1, bf_lo(k1.z), ax[4]);
        ax[5] = fmaf(e1, bf_hi(k1.z), ax[5]);
        ax[6] = fmaf(e1, bf_lo(k1.w), ax[6]);
        ax[7] = fmaf(e1, bf_hi(k1.w), ax[7]);
        den += e0 + e1;
    }
    if (i < end) {
        int s0 = csr_src[i];
        const unsigned* r0 = xl2b + (size_t)s0 * 24;
        float al0 = __uint_as_float(r0[20]) + add;
        uint4 k0 = *(const uint4*)(r0 + l * 4);
        al0 = fmaxf(al0, NEG_SLOPE * al0);
        float e0 = __builtin_amdgcn_exp2f(al0);
        ax[0] = fmaf(e0, bf_lo(k0.x), ax[0]);
        ax[1] = fmaf(e0, bf_hi(k0.x), ax[1]);
        ax[2] = fmaf(e0, bf_lo(k0.y), ax[2]);
        ax[3] = fmaf(e0, bf_hi(k0.y), ax[3]);
        ax[4] = fmaf(e0, bf_lo(k0.z), ax[4]);
        ax[5] = fmaf(e0, bf_hi(k0.z), ax[5]);
        ax[6] = fmaf(e0, bf_lo(k0.w), ax[6]);
        ax[7] = fmaf(e0, bf_hi(k0.w), ax[7]);
        den += e0;
    }

#pragma unroll
    for (int m = 8; m < 32; m <<= 1) {
#pragma unroll
        for (int j = 0; j < 8; j++) ax[j] += __shfl_xor(ax[j], m);
        den += __shfl_xor(den, m);
    }

    if (g == 0) {
        float inv = __builtin_amdgcn_rcpf(den + GAT_EPS);
        float* op = out + (size_t)d * 40 + l * 8;
        const float* bb = b2 + l * 8;
#pragma unroll
        for (int j = 0; j < 8; j++) op[j] = fmaf(ax[j], inv, bb[j]);
    }
}

extern "C" void kernel_launch(void* const* d_in, const int* in_sizes, int n_in,
                              void* d_out, int out_size, void* d_ws, size_t ws_size,
                              hipStream_t stream) {
    const float* x      = (const float*)d_in[0];
    const int*   ei     = (const int*)d_in[1];     // int32 on device
    const float* W1     = (const float*)d_in[2];
    const float* a_src1 = (const float*)d_in[3];
    const float* a_dst1 = (const float*)d_in[4];
    const float* b1     = (const float*)d_in[5];
    const float* W2     = (const float*)d_in[6];
    const float* a_src2 = (const float*)d_in[7];
    const float* a_dst2 = (const float*)d_in[8];
    const float* b2     = (const float*)d_in[9];

    int F = in_sizes[2] / 64;      // 128
    int N = in_sizes[0] / F;       // 100000
    int E = in_sizes[1] / 2;       // 1600000
    int Etot = E + N;
    int NCHv = (Etot + CH - 1) / CH;  // 831 chunks
    int shift = 8;                    // 256 nodes/bucket; 391 buckets used
    while (((N - 1) >> shift) >= NBK) shift++;  // safety (LDS supports shift<=10)

    // Workspace (4-byte words). h1 is gone (fused); xl2b/ad2 are separate
    // storage (xl1b/ad1 are still live while agg1 writes them). ~47 MB.
    unsigned* xl1b    = (unsigned*)d_ws;                   // N*32
    float*    as1     = (float*)(xl1b + (size_t)N * 32);   // N*8
    float*    ad1     = as1 + (size_t)N * 8;               // N*8
    int*      row_ptr = (int*)(ad1 + (size_t)N * 8);       // N+1
    int*      csr_src = row_ptr + (N + 1);                 // Etot
    unsigned* bslab   = (unsigned*)(csr_src + Etot);       // Etot
    int*      cnt     = (int*)(bslab + Etot);              // NCHv*NBK
    int*      off     = cnt + (size_t)NCHv * NBK;          // NCHv*NBK
    int*      tot     = off + (size_t)NCHv * NBK;          // NBK
    unsigned* xl2b    = (unsigned*)(tot + NBK);            // N*24 rows (96 B)
    float*    ad2     = (float*)(xl2b + (size_t)N * 24);   // N

    // ---- Layer-1 GEMM (256 nodes/block) + fused CSR pass A ----
    int gridG1 = (N + 255) / 256;
    if (gridG1 < NCHv) gridG1 = NCHv;
    k_gemm1<<<gridG1, 256, 0, stream>>>(x, W1, a_src1, a_dst1,
                                        xl1b, as1, ad1, N, F,
                                        ei, E, shift, NCHv, cnt);

    // ---- CSR build: deterministic counting sort, zero global atomics ----
    k_off_a<<<NBK, 256, 0, stream>>>(cnt, off, tot, NCHv);
    k_place<<<NCHv, 256, 0, stream>>>(ei, E, N, shift, off, tot, bslab);
    k_csr2 <<<NBK, 256, 0, stream>>>(tot, bslab, shift,
                                     row_ptr, csr_src, N, Etot);

    // ---- Layer-1 aggregation FUSED with layer-2 node transform ----
    k_agg1 <<<(N + 7) / 8, 256, 0, stream>>>(row_ptr, csr_src, as1, ad1,
                                             xl1b, b1, W2, a_src2, a_dst2,
                                             xl2b, ad2, N);

    // ---- Layer-2 aggregation ----
    k_agg2 <<<(N + 7) / 8, 256, 0, stream>>>(row_ptr, csr_src, ad2,
                                             xl2b, b2, (float*)d_out, N);
}